// Round 6
// baseline (887.311 us; speedup 1.0000x reference)
//
#include <hip/hip_runtime.h>

// Voxelizer: B=2, C=32 -> BC=64 channels, N=1e6 points, V=262144 voxels.
// v7 = v6 resubmission (round-5 failure was infra: "container failed twice",
// no kernel output; audit found no OOB/divergence/aliasing defect).
//   - reduce_mean: wave-per-voxel, lane=channel -> every sorted-row read is one
//     fully-coalesced 256B wave instruction (v5: 64x16B scattered per instr).
//   - voxel_gather: LDS transpose -> mean rows read 256B-coalesced (phase 1),
//     out written channel-coalesced + nontemporal (phase 2).
//   - permute_scatter: unchanged structure, nontemporal feat loads (no reuse).
//
// Pipeline: hist(1M atomics) -> in-place scan -> permute_scatter(1M atomics,
// coalesced feat read, 256B row writes) -> reduce_mean(0 atomics) -> gather.
//
// ws (68,157,440 B budget):
//   mean   : float[V*BC] @ 0          (67,108,864 B) [v][bc] rows
//   cursor : int[V]      @ 67,108,864 ( 1,048,576 B)
//   partials aliases mean[0..255] (dead until reduce_mean; scan done by then)
// d_out (256,000,000 B) holds sorted[N][BC] until the final gather overwrites.

constexpr int BC  = 64;
constexpr int VOX = 262144;
constexpr int SCAN_BLK = 1024;            // elements per scan block
constexpr int NSB = VOX / SCAN_BLK;       // 256
constexpr int WV  = 8;                    // voxels per wave in reduce

__global__ __launch_bounds__(256) void hist_kernel(
    const int* __restrict__ idx, int* __restrict__ cursor, int N)
{
    int t = blockIdx.x * 256 + threadIdx.x;
    int n0 = t * 4;
    if (n0 >= N) return;
    int4 vi = *(const int4*)(idx + n0);
    atomicAdd(&cursor[vi.x], 1);
    atomicAdd(&cursor[vi.y], 1);
    atomicAdd(&cursor[vi.z], 1);
    atomicAdd(&cursor[vi.w], 1);
}

// In-place exclusive scan of cursor (each thread reads only its own int4
// before writing -> in-place safe).
__global__ __launch_bounds__(256) void scan_blocks(
    int* __restrict__ cursor, int* __restrict__ partials)
{
    __shared__ int sm[256];
    int t = threadIdx.x, b = blockIdx.x;
    int base = b * SCAN_BLK + t * 4;
    int4 c = *(const int4*)(cursor + base);
    int s = c.x + c.y + c.z + c.w;
    sm[t] = s;
    __syncthreads();
    #pragma unroll
    for (int off = 1; off < 256; off <<= 1) {
        int add = (t >= off) ? sm[t - off] : 0;
        __syncthreads();
        sm[t] += add;
        __syncthreads();
    }
    int excl = sm[t] - s;
    int4 o;
    o.x = excl; o.y = excl + c.x; o.z = o.y + c.y; o.w = o.z + c.z;
    *(int4*)(cursor + base) = o;
    if (t == 255) partials[b] = sm[255];
}

__global__ __launch_bounds__(256) void scan_partials(int* __restrict__ partials)
{
    __shared__ int sm[256];
    int t = threadIdx.x;
    int v = partials[t];
    sm[t] = v;
    __syncthreads();
    #pragma unroll
    for (int off = 1; off < 256; off <<= 1) {
        int add = (t >= off) ? sm[t - off] : 0;
        __syncthreads();
        sm[t] += add;
        __syncthreads();
    }
    partials[t] = sm[t] - v;              // exclusive
}

__global__ __launch_bounds__(256) void scan_add(
    int* __restrict__ cursor, const int* __restrict__ partials)
{
    int t = blockIdx.x * 256 + threadIdx.x;
    int base = t * 4;                     // 1024 % 4 == 0 -> same partial
    int add = partials[base >> 10];
    int4 c = *(int4*)(cursor + base);
    c.x += add; c.y += add; c.z += add; c.w += add;
    *(int4*)(cursor + base) = c;
}

// Per point p: allocate slot j in its voxel's segment, gather the point's 64
// channels (coalesced across lanes), write one contiguous 256B row.
__global__ __launch_bounds__(256) void permute_scatter(
    const float* __restrict__ feat, const int* __restrict__ idx,
    int* __restrict__ cursor, float* __restrict__ sorted, int N)
{
    int p = blockIdx.x * 256 + threadIdx.x;
    if (p >= N) return;
    int v = idx[p];
    int j = atomicAdd(&cursor[v], 1);     // after kernel: cursor[v] == end
    float* dst = sorted + (size_t)j * BC; // 256B-aligned row

    #pragma unroll
    for (int c0 = 0; c0 < BC; c0 += 16) { // 16-float chunks: low VGPR
        float f[16];
        #pragma unroll
        for (int k = 0; k < 16; ++k)      // nt: feat never re-read; spare L3
            f[k] = __builtin_nontemporal_load(&feat[(size_t)(c0 + k) * N + p]);
        #pragma unroll
        for (int q = 0; q < 4; ++q)
            *(float4*)(dst + c0 + 4 * q) =
                make_float4(f[4*q], f[4*q+1], f[4*q+2], f[4*q+3]);
    }
}

// Wave-per-voxel, lane=channel: every sorted-row read is one coalesced 256B
// wave instruction; mean row write is one coalesced 256B wave instruction.
// end(v_i) == start(v_{i+1}) -> one uniform cursor load per voxel.
__global__ __launch_bounds__(256) void reduce_mean(
    const float* __restrict__ sorted, const int* __restrict__ cursor,
    float* __restrict__ mean)
{
    int wave = (blockIdx.x * 256 + threadIdx.x) >> 6;
    int lane = threadIdx.x & 63;
    int v0 = wave * WV;

    int start = (v0 > 0) ? cursor[v0 - 1] : 0;
    for (int i = 0; i < WV; ++i) {
        int v = v0 + i;
        int end = cursor[v];              // uniform; broadcast
        float acc = 0.f;
        for (int j = start; j < end; ++j)
            acc += sorted[(size_t)j * BC + lane];   // coalesced 256B/instr
        float inv = 1.0f / fmaxf((float)(end - start), 1.0f);
        mean[(size_t)v * BC + lane] = acc * inv;    // coalesced 256B/instr
        start = end;
    }
}

// LDS transpose gather: phase 1 reads mean rows 256B-coalesced (voxel id
// broadcast via shfl), phase 2 writes out channel-coalesced + nontemporal.
__global__ __launch_bounds__(256) void voxel_gather(
    const float* __restrict__ mean, const int* __restrict__ idx,
    float* __restrict__ out, int N)
{
    __shared__ float tile[256][BC + 1];   // pad: phase-2 stride-65 reads are
                                          // bank = tid%32 -> 2-way (free)
    int tid = threadIdx.x;
    int wave = tid >> 6, lane = tid & 63;
    int p0 = blockIdx.x * 256;

    // explicit per-wave trip count (tail block): rows this wave must fill
    int wbase = p0 + wave * 64;
    int wcount = N - wbase;               // may exceed 64; clamp
    if (wcount > 64) wcount = 64;

    // phase 1: each wave loads wcount point-rows, one row per coalesced instr
    int pme = wbase + lane;
    int vme = (pme < N) ? idx[pme] : 0;   // coalesced idx load
    for (int i = 0; i < wcount; ++i) {    // wave-uniform trip count
        int v = __shfl(vme, i);
        tile[wave * 64 + i][lane] = mean[(size_t)v * BC + lane];
    }
    __syncthreads();

    // phase 2: thread-per-point, 64 channel-coalesced nt stores
    int p = p0 + tid;
    if (p < N) {
        #pragma unroll
        for (int c = 0; c < BC; ++c)
            __builtin_nontemporal_store(tile[tid][c], &out[(size_t)c * N + p]);
    }
}

extern "C" void kernel_launch(void* const* d_in, const int* in_sizes, int n_in,
                              void* d_out, int out_size, void* d_ws, size_t ws_size,
                              hipStream_t stream) {
    const float* feat = (const float*)d_in[0];
    const int* idx = (const int*)d_in[1];
    float* out = (float*)d_out;
    int N = in_sizes[1];                  // 1,000,000

    float* mean = (float*)d_ws;                                   // 64MB
    int* cursor = (int*)((char*)d_ws + (size_t)VOX * BC * 4);     // 1MB
    int* partials = (int*)d_ws;           // aliases mean head; dead until
                                          // reduce_mean (scan done by then)
    float* sorted = (float*)d_out;        // 256MB; overwritten by gather

    hipMemsetAsync(cursor, 0, (size_t)VOX * sizeof(int), stream);

    int pblocks4 = ((N + 3) / 4 + 255) / 256;   // 977
    int pblocks1 = (N + 255) / 256;             // 3907

    hist_kernel    <<<pblocks4, 256, 0, stream>>>(idx, cursor, N);
    scan_blocks    <<<NSB, 256, 0, stream>>>(cursor, partials);
    scan_partials  <<<1, 256, 0, stream>>>(partials);
    scan_add       <<<VOX / SCAN_BLK, 256, 0, stream>>>(cursor, partials);
    permute_scatter<<<pblocks1, 256, 0, stream>>>(feat, idx, cursor, sorted, N);
    reduce_mean    <<<VOX / (WV * 4), 256, 0, stream>>>(sorted, cursor, mean);
    voxel_gather   <<<pblocks1, 256, 0, stream>>>(mean, idx, out, N);
}